// Round 1
// baseline (317.733 us; speedup 1.0000x reference)
//
#include <hip/hip_runtime.h>

// MaskedAttention: B=4,S=1024,W=1024,H=16,DH=64. Softmax over HEAD axis.
// Pipeline: cvt->bf16, QKV mfma GEMM (V stored transposed), fused attn
// (per-(q,k) 16-way head softmax fully in-register), out mfma GEMM.

typedef float f32x4 __attribute__((ext_vector_type(4)));
typedef __bf16 bf16x8 __attribute__((ext_vector_type(8)));

__device__ __forceinline__ unsigned short f2bf(float f){
  unsigned int u = __builtin_bit_cast(unsigned int, f);
  u = (u + 0x7FFFu + ((u >> 16) & 1u)) >> 16;
  return (unsigned short)u;
}

__global__ __launch_bounds__(256) void cvt_kernel(const float* __restrict__ s,
                                                  unsigned short* __restrict__ d, int n4){
  int i = blockIdx.x * 256 + threadIdx.x;
  if (i < n4){
    float4 v = ((const float4*)s)[i];
    ushort4 o;
    o.x = f2bf(v.x); o.y = f2bf(v.y); o.z = f2bf(v.z); o.w = f2bf(v.w);
    ((ushort4*)d)[i] = o;
  }
}

// ---------------- GEMM: C[m,n] = sum_k A[m,k]*Wt[n,k] (+bias) -----------------
// A row-major [M][K] bf16, Wt row-major [N][K] bf16 (torch Linear weight layout).
// MODE 0: outp[m*N+n] = acc + bias0[n]  (f32)
// MODE 1: QKV epilogue -> qws/kws [b][h][s][d], vws transposed [b][h][d][s] (bf16)
#define BM 128
#define BN 128
#define BK 32
#define LDP 40  // padded LDS row stride (elems): 80B -> conflict-free frag reads

template<int MODE>
__global__ __launch_bounds__(256) void gemm_bt(
    const unsigned short* __restrict__ A, const unsigned short* __restrict__ Wt,
    int M, int N, int K,
    float* __restrict__ outp,
    unsigned short* __restrict__ qws, unsigned short* __restrict__ kws,
    unsigned short* __restrict__ vws,
    const float* __restrict__ bias0, const float* __restrict__ bias1,
    const float* __restrict__ bias2)
{
  __shared__ unsigned short Asm_[BM*LDP];
  __shared__ unsigned short Wsm_[BN*LDP];
  const int tid = threadIdx.x;
  const int lane = tid & 63;
  const int wid = tid >> 6;
  const int wr = wid >> 1, wc = wid & 1;     // 2x2 wave grid, 64x64 out each
  const int m0 = blockIdx.x * BM, n0 = blockIdx.y * BN;
  const int lq = lane & 15, lg = lane >> 4;
  const int r0 = tid >> 2;                   // staging row (0..63)
  const int cb = (tid & 3) * 8;              // staging col (elems)
  f32x4 acc[4][4] = {};

  for (int k0 = 0; k0 < K; k0 += BK){
    uint4 av0 = *(const uint4*)(A  + (size_t)(m0 + r0)*K      + k0 + cb);
    uint4 wv0 = *(const uint4*)(Wt + (size_t)(n0 + r0)*K      + k0 + cb);
    uint4 av1 = *(const uint4*)(A  + (size_t)(m0 + r0 + 64)*K + k0 + cb);
    uint4 wv1 = *(const uint4*)(Wt + (size_t)(n0 + r0 + 64)*K + k0 + cb);
    *(uint4*)(&Asm_[ r0      *LDP + cb]) = av0;
    *(uint4*)(&Wsm_[ r0      *LDP + cb]) = wv0;
    *(uint4*)(&Asm_[(r0 + 64)*LDP + cb]) = av1;
    *(uint4*)(&Wsm_[(r0 + 64)*LDP + cb]) = wv1;
    __syncthreads();
    bf16x8 af[4], wf[4];
    #pragma unroll
    for (int i = 0; i < 4; ++i){
      af[i] = *(const bf16x8*)(&Asm_[(wr*64 + i*16 + lq)*LDP + lg*8]);
      wf[i] = *(const bf16x8*)(&Wsm_[(wc*64 + i*16 + lq)*LDP + lg*8]);
    }
    #pragma unroll
    for (int i = 0; i < 4; ++i)
      #pragma unroll
      for (int j = 0; j < 4; ++j)
        acc[i][j] = __builtin_amdgcn_mfma_f32_16x16x32_bf16(af[i], wf[j], acc[i][j], 0, 0, 0);
    __syncthreads();
  }

  if (MODE == 0){
    #pragma unroll
    for (int j = 0; j < 4; ++j){
      int ncol = n0 + wc*64 + j*16 + lq;
      float bv = bias0[ncol];
      #pragma unroll
      for (int i = 0; i < 4; ++i){
        int mrow = m0 + wr*64 + i*16 + lg*4;
        #pragma unroll
        for (int r = 0; r < 4; ++r)
          outp[(size_t)(mrow + r)*N + ncol] = acc[i][j][r] + bv;
      }
    }
  } else {
    const int sel = n0 >> 10;   // uniform per block: 0=Q 1=K 2=V
    const float* bp = (sel == 0) ? bias0 : ((sel == 1) ? bias1 : bias2);
    #pragma unroll
    for (int j = 0; j < 4; ++j){
      int n  = n0 + wc*64 + j*16 + lq;
      int n1 = n & 1023;
      int h = n1 >> 6, d = n1 & 63;
      float bv = bp[n1];
      #pragma unroll
      for (int i = 0; i < 4; ++i){
        int mbase = m0 + wr*64 + i*16 + lg*4;
        #pragma unroll
        for (int r = 0; r < 4; ++r){
          int m = mbase + r;
          int b = m >> 10, s = m & 1023;
          unsigned short o = f2bf(acc[i][j][r] + bv);
          if (sel == 0)      qws[(size_t)((((b<<4) + h)<<10) + s)*64 + d] = o;
          else if (sel == 1) kws[(size_t)((((b<<4) + h)<<10) + s)*64 + d] = o;
          else               vws[(size_t)((((b<<4) + h)<<6) + d)*1024 + s] = o;
        }
      }
    }
  }
}

// ---------------- fused attention -----------------
// grid: 256 blocks = (b, 16-row q tile); 8 waves.
// Per iter (128 k's): wave w computes QK for k-chunk w (16 cols) x ALL 16 heads
// -> head-softmax fully in-register -> P to LDS (XOR-swizzled) -> barrier ->
// PV with 2 heads/wave over all 128 k's.
__global__ __launch_bounds__(512) void attn_kernel(
    const unsigned short* __restrict__ qws, const unsigned short* __restrict__ kws,
    const unsigned short* __restrict__ vws, const int* __restrict__ mask,
    unsigned short* __restrict__ xout)
{
  extern __shared__ unsigned short smem[];
  unsigned short* Qs = smem;           // [16h][16q][64d], 32KB, swz ((q&7)<<4)
  unsigned short* Ps = smem + 16384;   // [16h][16q][128k], 64KB, swz ((q&7)<<4)
  const int tid = threadIdx.x;
  const int lane = tid & 63, w = tid >> 6;
  const int b = blockIdx.x >> 6, qt = blockIdx.x & 63;
  const int q0 = qt << 4;
  const int lq = lane & 15, lg = lane >> 4;
  const int aswz = (lq & 7) << 4;

  // stage Q tile (all heads) into LDS
  for (int c = tid; c < 2048; c += 512){
    int e = c << 3;
    int h = e >> 10, q = (e >> 6) & 15, d0 = e & 63;
    uint4 v = *(const uint4*)(qws + (size_t)((((b<<4) + h)<<10) + q0 + q)*64 + d0);
    int byteoff = (((h<<10) + (q<<6) + d0) << 1) ^ ((q & 7) << 4);
    *(uint4*)((char*)Qs + byteoff) = v;
  }
  __syncthreads();

  f32x4 acc[2][4] = {};
  const float kscale = 0.125f * 1.44269504f;  // softmax over scaled scores via exp2

  for (int it = 0; it < 8; ++it){
    const int kb = (it << 7) + (w << 4);      // this wave's global k base
    // ---- QK^T: 16 heads, 16 k cols, K(reduce)=64
    f32x4 sc[16];
    #pragma unroll
    for (int h = 0; h < 16; ++h){
      int abase = (h << 11) + (lq << 7) + (lg << 4);
      bf16x8 a0 = *(const bf16x8*)((const char*)Qs + ((abase     ) ^ aswz));
      bf16x8 a1 = *(const bf16x8*)((const char*)Qs + ((abase + 64) ^ aswz));
      const unsigned short* kp = kws + (size_t)((((b<<4) + h)<<10) + kb + lq)*64 + (lg<<3);
      bf16x8 kf0 = *(const bf16x8*)(kp);
      bf16x8 kf1 = *(const bf16x8*)(kp + 32);
      f32x4 s = {};
      s = __builtin_amdgcn_mfma_f32_16x16x32_bf16(a0, kf0, s, 0, 0, 0);
      s = __builtin_amdgcn_mfma_f32_16x16x32_bf16(a1, kf1, s, 0, 0, 0);
      sc[h] = s;
    }
    // ---- head-softmax (16 values per (q,k), all in-register) + P->LDS
    const int* mp = mask + (size_t)((b<<10) + q0 + (lg<<2))*1024 + (it<<7) + (w<<4) + lq;
    #pragma unroll
    for (int r = 0; r < 4; ++r){
      const int mv = mp[r << 10];
      float mx = sc[0][r];
      #pragma unroll
      for (int h = 1; h < 16; ++h) mx = fmaxf(mx, sc[h][r]);
      float e[16]; float sum = 0.f;
      #pragma unroll
      for (int h = 0; h < 16; ++h){
        e[h] = __builtin_amdgcn_exp2f((sc[h][r] - mx) * kscale);
        sum += e[h];
      }
      const float rs = __builtin_amdgcn_rcpf(sum);
      const int q = (lg << 2) + r;
      const int pswz = (q & 7) << 4;
      const int pcol = ((w << 4) + lq) << 1;
      #pragma unroll
      for (int h = 0; h < 16; ++h){
        float pv = mv ? (e[h] * rs) : 0.0625f;  // all-masked => uniform 1/16 exactly
        *(unsigned short*)((char*)Ps + (((h << 12) + (q << 8) + pcol) ^ pswz)) = f2bf(pv);
      }
    }
    __syncthreads();
    // ---- PV: 2 heads per wave, k(reduce)=128, d=64
    #pragma unroll
    for (int hh = 0; hh < 2; ++hh){
      const int h = (w << 1) + hh;
      #pragma unroll
      for (int kp4 = 0; kp4 < 4; ++kp4){
        int pbyte = ((h << 12) + (lq << 8) + (kp4 << 6) + (lg << 4)) ^ aswz;
        bf16x8 pa = *(const bf16x8*)((const char*)Ps + pbyte);
        #pragma unroll
        for (int dc = 0; dc < 4; ++dc){
          const unsigned short* vp = vws + (size_t)((((b<<4) + h)<<6) + (dc<<4) + lq)*1024
                                   + (it<<7) + (kp4<<5) + (lg<<3);
          bf16x8 bv = *(const bf16x8*)(vp);
          acc[hh][dc] = __builtin_amdgcn_mfma_f32_16x16x32_bf16(pa, bv, acc[hh][dc], 0, 0, 0);
        }
      }
    }
    __syncthreads();
  }
  // ---- write x [B,S,1024] bf16 (merged heads)
  #pragma unroll
  for (int hh = 0; hh < 2; ++hh){
    const int h = (w << 1) + hh;
    #pragma unroll
    for (int dc = 0; dc < 4; ++dc){
      #pragma unroll
      for (int r = 0; r < 4; ++r){
        int row = q0 + (lg << 2) + r;
        int col = (h << 6) + (dc << 4) + lq;
        xout[(size_t)((b << 10) + row)*1024 + col] = f2bf(acc[hh][dc][r]);
      }
    }
  }
}

extern "C" void kernel_launch(void* const* d_in, const int* in_sizes, int n_in,
                              void* d_out, int out_size, void* d_ws, size_t ws_size,
                              hipStream_t stream) {
  const float* inp = (const float*)d_in[0];
  const int*  mask = (const int*)d_in[1];
  const float* wq = (const float*)d_in[2];
  const float* bq = (const float*)d_in[3];
  const float* wk = (const float*)d_in[4];
  const float* bk = (const float*)d_in[5];
  const float* wv = (const float*)d_in[6];
  const float* bv = (const float*)d_in[7];
  const float* wo = (const float*)d_in[8];
  const float* bo = (const float*)d_in[9];
  float* out = (float*)d_out;

  char* ws = (char*)d_ws;
  unsigned short* inp_bf = (unsigned short*)(ws);                    // 8MB
  unsigned short* wqkv   = (unsigned short*)(ws + (8u  << 20));      // 6MB (wq;wk;wv)
  unsigned short* wo_bf  = (unsigned short*)(ws + (14u << 20));      // 2MB
  unsigned short* qws    = (unsigned short*)(ws + (16u << 20));      // 8MB [b][h][s][d]
  unsigned short* kws    = (unsigned short*)(ws + (24u << 20));      // 8MB [b][h][s][d]
  unsigned short* vws    = (unsigned short*)(ws + (32u << 20));      // 8MB [b][h][d][s]
  unsigned short* xbf    = (unsigned short*)(ws + (40u << 20));      // 8MB

  cvt_kernel<<<4096, 256, 0, stream>>>(inp, inp_bf, 1048576);
  cvt_kernel<<<1024, 256, 0, stream>>>(wq, wqkv,               262144);
  cvt_kernel<<<1024, 256, 0, stream>>>(wk, wqkv + (1u << 20),  262144);
  cvt_kernel<<<1024, 256, 0, stream>>>(wv, wqkv + (2u << 20),  262144);
  cvt_kernel<<<1024, 256, 0, stream>>>(wo, wo_bf, 262144);

  gemm_bt<1><<<dim3(32, 24), 256, 0, stream>>>(inp_bf, wqkv, 4096, 3072, 1024,
                                               nullptr, qws, kws, vws, bq, bk, bv);
  attn_kernel<<<256, 512, 98304, stream>>>(qws, kws, vws, mask, xbf);
  gemm_bt<0><<<dim3(32, 8), 256, 0, stream>>>(xbf, wo_bf, 4096, 1024, 1024,
                                              out, nullptr, nullptr, nullptr, bo, nullptr, nullptr);
}